// Round 4
// baseline (541.898 us; speedup 1.0000x reference)
//
#include <hip/hip_runtime.h>
#include <math.h>

#define NEG_INF -1e30f

struct AttnLds {
  float Ks[256][32];
  float Vt[32][260];
  float ps[4][256];
  float qs[16][32];
  float wks[5][32];   // wr_k rows j=0..3, row4 = br_k  (head h)
  float wvs[5][32];   // wr_v rows j=0..3, row4 = br_v
};
struct GemmLds {
  float At[32][34];   // [k][m], pad 34
  float Bs[32][64];
};
union MegaLds {
  AttnLds a;
  GemmLds g;
  float pad[20608];   // 82432 B total: 2 blocks > 160 KiB -> exactly 1 block/CU
};

// Device-scope grid barrier: monotonic counter, zeroed by memset node each launch.
__device__ __forceinline__ void gbar(unsigned* cnt, unsigned expect) {
  __syncthreads();                     // all waves drain their vmcnt before arrive
  if (threadIdx.x == 0) {
    __threadfence();                   // release: wb this XCD's L2 (sc1)
    __hip_atomic_fetch_add(cnt, 1u, __ATOMIC_RELEASE, __HIP_MEMORY_SCOPE_AGENT);
    while (__hip_atomic_load(cnt, __ATOMIC_RELAXED, __HIP_MEMORY_SCOPE_AGENT) < expect)
      __builtin_amdgcn_s_sleep(2);
    __threadfence();                   // acquire: inv L1 + this XCD's L2
  }
  __syncthreads();
}

// 32x64 tile GEMM core, 2x4 micro, 256 threads, KC=32
__device__ __forceinline__ void gemm32(MegaLds& L,
    const float* __restrict__ A, int lda,
    const float* __restrict__ Bw, int ldb,
    int kbeg, int kend, int m0, int n0, float acc[2][4])
{
  float (&At)[32][34] = L.g.At;
  float (&Bs)[32][64] = L.g.Bs;
  int tid = threadIdx.x;
  int r  = tid >> 3;             // 0..31 : A row / B k-row
  int c4 = tid & 7;              // chunk
  int tx = tid & 15, ty = tid >> 4;
  for (int kc = kbeg; kc < kend; kc += 32) {
    float4 a = *(const float4*)(A + (size_t)(m0 + r) * lda + kc + c4 * 4);
    const float* bp = Bw + (size_t)(kc + r) * ldb + n0;
    float4 b0  = *(const float4*)(bp + c4 * 4);
    float4 b1v = *(const float4*)(bp + 32 + c4 * 4);
    At[c4*4+0][r] = a.x; At[c4*4+1][r] = a.y; At[c4*4+2][r] = a.z; At[c4*4+3][r] = a.w;
    *(float4*)&Bs[r][c4*4]      = b0;
    *(float4*)&Bs[r][32 + c4*4] = b1v;
    __syncthreads();
#pragma unroll
    for (int k = 0; k < 32; ++k) {
      float2 av = *(const float2*)&At[k][ty * 2];
      float4 bv = *(const float4*)&Bs[k][tx * 4];
      acc[0][0] = fmaf(av.x, bv.x, acc[0][0]); acc[0][1] = fmaf(av.x, bv.y, acc[0][1]);
      acc[0][2] = fmaf(av.x, bv.z, acc[0][2]); acc[0][3] = fmaf(av.x, bv.w, acc[0][3]);
      acc[1][0] = fmaf(av.y, bv.x, acc[1][0]); acc[1][1] = fmaf(av.y, bv.y, acc[1][1]);
      acc[1][2] = fmaf(av.y, bv.z, acc[1][2]); acc[1][3] = fmaf(av.y, bv.w, acc[1][3]);
    }
    __syncthreads();
  }
}

__global__ __launch_bounds__(256, 1) void mega_kernel(
    const float* __restrict__ src, const float* __restrict__ tgt,
    const float* __restrict__ rpe,
    const int* __restrict__ smask, const int* __restrict__ tmask,
    const float* __restrict__ ln1g, const float* __restrict__ ln1b,
    const float* __restrict__ lntg, const float* __restrict__ lntb,
    const float* __restrict__ ln2g, const float* __restrict__ ln2b,
    const float* __restrict__ wq, const float* __restrict__ bq,
    const float* __restrict__ wk, const float* __restrict__ bk,
    const float* __restrict__ wv, const float* __restrict__ bv,
    const float* __restrict__ wo, const float* __restrict__ bo,
    const float* __restrict__ wr, const float* __restrict__ br,
    const float* __restrict__ w1, const float* __restrict__ b1,
    const float* __restrict__ w2, const float* __restrict__ b2,
    float* __restrict__ ws, float* __restrict__ out, unsigned* __restrict__ cnt)
{
  __shared__ MegaLds L;
  int tid = threadIdx.x, bx = blockIdx.x;
  int w = tid >> 6, lane = tid & 63;
  unsigned bi = 0;

  float* S2   = ws;
  float* TN   = ws + 131072;
  float* Qb   = ws + 262144;
  float* Kb   = ws + 393216;
  float* Vb   = ws + 524288;
  float* AO   = ws + 655360;
  float* X    = ws + 786432;
  float* XN   = ws + 917504;
  float* SRC1 = ws + 1048576;
  float* H1   = ws + 1179648;

  for (int l = 0; l < 2; ++l) {
    const float* srcin = l ? SRC1 : src;
    float* outb = l ? out : SRC1;
    const float* g1 = ln1g + l*256; const float* be1 = ln1b + l*256;
    const float* gt = lntg + l*256; const float* bet = lntb + l*256;
    const float* g2 = ln2g + l*256; const float* be2 = ln2b + l*256;
    const float* wq_l = wq + l*65536; const float* bq_l = bq + l*256;
    const float* wk_l = wk + l*65536; const float* bk_l = bk + l*256;
    const float* wv_l = wv + l*65536; const float* bv_l = bv + l*256;
    const float* wo_l = wo + l*65536; const float* bo_l = bo + l*256;
    const float* wr_l = wr + l*2048;  const float* br_l = br + l*512;
    const float* w1_l = w1 + l*262144; const float* b1_l = b1 + l*1024;
    const float* w2_l = w2 + l*262144; const float* b2_l = b2 + l*256;

    // ---- S1: LN(src)->S2, LN(tgt)->TN, X := src + bo ----
    {
      int task = bx * 4 + w;                 // 0..1023, one row per wave
      bool issrc = task < 512;
      int r = issrc ? task : task - 512;
      const float* xrow = issrc ? srcin + r * 256 : tgt + r * 256;
      float* orow       = issrc ? S2 + r * 256    : TN + r * 256;
      const float* g    = issrc ? g1 : gt;
      const float* bb   = issrc ? be1 : bet;
      float4 v = ((const float4*)xrow)[lane];
      float s  = v.x + v.y + v.z + v.w;
      float ss = v.x*v.x + v.y*v.y + v.z*v.z + v.w*v.w;
#pragma unroll
      for (int off = 32; off >= 1; off >>= 1) {
        s  += __shfl_xor(s,  off);
        ss += __shfl_xor(ss, off);
      }
      float mean = s * (1.0f / 256.0f);
      float var  = ss * (1.0f / 256.0f) - mean * mean;
      float rstd = rsqrtf(var + 1e-5f);
      float4 gg = ((const float4*)g)[lane];
      float4 b4 = ((const float4*)bb)[lane];
      float4 ov;
      ov.x = (v.x - mean) * rstd * gg.x + b4.x;
      ov.y = (v.y - mean) * rstd * gg.y + b4.y;
      ov.z = (v.z - mean) * rstd * gg.z + b4.z;
      ov.w = (v.w - mean) * rstd * gg.w + b4.w;
      ((float4*)orow)[lane] = ov;
      if (issrc) {
        float4 bov = ((const float4*)bo_l)[lane];
        float4 xi;
        xi.x = v.x + bov.x; xi.y = v.y + bov.y; xi.z = v.z + bov.z; xi.w = v.w + bov.w;
        ((float4*)(X + r * 256))[lane] = xi;
      }
    }
    gbar(cnt, ++bi * 256u);

    // ---- S2: QKV GEMM (192 tiles) ----
    if (bx < 192) {
      int z = bx >> 6, u = bx & 63;
      int m0 = (u >> 2) * 32, n0 = (u & 3) * 64;
      const float* A    = (z == 0) ? S2 : TN;
      const float* Bw   = (z == 0) ? wq_l : (z == 1) ? wk_l : wv_l;
      const float* bias = (z == 0) ? bq_l : (z == 1) ? bk_l : bv_l;
      float acc[2][4] = {};
      gemm32(L, A, 256, Bw, 256, 0, 256, m0, n0, acc);
      int tx = tid & 15, ty = tid >> 4;
      int c0 = n0 + tx * 4;
      const float scale = 0.1767766952966369f;   // 1/sqrt(32)
#pragma unroll
      for (int i = 0; i < 2; ++i) {
        int m = m0 + ty * 2 + i;
        float4 r;
        r.x = acc[i][0] + bias[c0 + 0];
        r.y = acc[i][1] + bias[c0 + 1];
        r.z = acc[i][2] + bias[c0 + 2];
        r.w = acc[i][3] + bias[c0 + 3];
        if (z == 0) {
          r.x *= scale; r.y *= scale; r.z *= scale; r.w *= scale;
          *(float4*)&Qb[m * 256 + c0] = r;
        } else {
          int b = m >> 8, t = m & 255, h = c0 >> 5, d0 = c0 & 31;
          float* dst = ((z == 1) ? Kb : Vb) + (size_t)(b * 8 + h) * 8192 + t * 32 + d0;
          *(float4*)dst = r;
        }
      }
    }
    gbar(cnt, ++bi * 256u);

    // ---- S3: attention (256 tiles = (b,h,16 s-rows)) ----
    {
      int b = bx >> 7, h = (bx >> 4) & 7, s0 = (bx & 15) << 4;
      const float* Kp = Kb + (size_t)(b * 8 + h) * 8192;
      const float* Vp = Vb + (size_t)(b * 8 + h) * 8192;
      {
        int t = tid;
        const float4* kr = (const float4*)(Kp + t * 32);
        const float4* vr = (const float4*)(Vp + t * 32);
        int sw = t & 7;
#pragma unroll
        for (int c = 0; c < 8; ++c) {
          float4 k4 = kr[c];
          *(float4*)&L.a.Ks[t][(c ^ sw) * 4] = k4;
        }
#pragma unroll
        for (int c = 0; c < 8; ++c) {
          float4 v4 = vr[c];
          L.a.Vt[c*4+0][t] = v4.x; L.a.Vt[c*4+1][t] = v4.y;
          L.a.Vt[c*4+2][t] = v4.z; L.a.Vt[c*4+3][t] = v4.w;
        }
      }
      if (tid < 160) {
        int j = tid >> 5, d = tid & 31;
        L.a.wks[j][d] = (j < 4) ? wr_l[j * 512 + h * 32 + d]       : br_l[h * 32 + d];
        L.a.wvs[j][d] = (j < 4) ? wr_l[j * 512 + 256 + h * 32 + d] : br_l[256 + h * 32 + d];
      }
      if (tid >= 128) {
        int u = tid - 128;
        int rr2 = u >> 3, cc = u & 7;
        *(float4*)&L.a.qs[rr2][cc*4] =
            *(const float4*)&Qb[(b * 256 + s0 + rr2) * 256 + h * 32 + cc * 4];
      }
      __syncthreads();

      int msk[4];
#pragma unroll
      for (int it = 0; it < 4; ++it) msk[it] = tmask[b * 256 + it * 64 + lane];

      for (int i = 0; i < 4; ++i) {
        int sl = w * 4 + i;
        int s = s0 + sl;
        float4 q4[8];
#pragma unroll
        for (int c = 0; c < 8; ++c) q4[c] = *(const float4*)&L.a.qs[sl][c * 4];
        float qw[4]; float qbr = 0.0f;
#pragma unroll
        for (int j = 0; j < 4; ++j) {
          float t0 = 0;
#pragma unroll
          for (int c = 0; c < 8; ++c) {
            float4 wv4 = *(const float4*)&L.a.wks[j][c * 4];
            t0 += q4[c].x*wv4.x + q4[c].y*wv4.y + q4[c].z*wv4.z + q4[c].w*wv4.w;
          }
          qw[j] = t0;
        }
#pragma unroll
        for (int c = 0; c < 8; ++c) {
          float4 wv4 = *(const float4*)&L.a.wks[4][c * 4];
          qbr += q4[c].x*wv4.x + q4[c].y*wv4.y + q4[c].z*wv4.z + q4[c].w*wv4.w;
        }
        const float4* rp4 = (const float4*)(rpe + (size_t)(b * 256 + s) * 1024);
        float sc[4]; float4 rr[4];
#pragma unroll
        for (int it = 0; it < 4; ++it) {
          int t = it * 64 + lane;
          int sw = t & 7;
          float sv = 0;
#pragma unroll
          for (int c = 0; c < 8; ++c) {
            float4 k4 = *(const float4*)&L.a.Ks[t][(c ^ sw) * 4];
            sv = fmaf(q4[c].x, k4.x, sv); sv = fmaf(q4[c].y, k4.y, sv);
            sv = fmaf(q4[c].z, k4.z, sv); sv = fmaf(q4[c].w, k4.w, sv);
          }
          float4 rv = rp4[t];
          rr[it] = rv;
          sv += rv.x*qw[0] + rv.y*qw[1] + rv.z*qw[2] + rv.w*qw[3] + qbr;
          if (msk[it] != 0) sv = NEG_INF;
          sc[it] = sv;
        }
        float mval = fmaxf(fmaxf(sc[0], sc[1]), fmaxf(sc[2], sc[3]));
#pragma unroll
        for (int off = 32; off >= 1; off >>= 1) mval = fmaxf(mval, __shfl_xor(mval, off));
        float p[4], lsum = 0;
#pragma unroll
        for (int it = 0; it < 4; ++it) { p[it] = __expf(sc[it] - mval); lsum += p[it]; }
        float wj0 = 0, wj1 = 0, wj2 = 0, wj3 = 0;
#pragma unroll
        for (int it = 0; it < 4; ++it) {
          wj0 = fmaf(p[it], rr[it].x, wj0);
          wj1 = fmaf(p[it], rr[it].y, wj1);
          wj2 = fmaf(p[it], rr[it].z, wj2);
          wj3 = fmaf(p[it], rr[it].w, wj3);
        }
#pragma unroll
        for (int off = 32; off >= 1; off >>= 1) {
          lsum += __shfl_xor(lsum, off);
          wj0 += __shfl_xor(wj0, off);
          wj1 += __shfl_xor(wj1, off);
          wj2 += __shfl_xor(wj2, off);
          wj3 += __shfl_xor(wj3, off);
        }
#pragma unroll
        for (int it = 0; it < 4; ++it) L.a.ps[w][it * 64 + lane] = p[it];
        int g = lane >> 5, d = lane & 31;
        float o = 0;
#pragma unroll
        for (int n = 0; n < 32; ++n) {
          int t = g * 128 + n * 4;
          float4 p4 = *(const float4*)&L.a.ps[w][t];
          float4 v4 = *(const float4*)&L.a.Vt[d][t];
          o += p4.x*v4.x + p4.y*v4.y + p4.z*v4.z + p4.w*v4.w;
        }
        o += __shfl_xor(o, 32);
        float corr = wj0 * L.a.wvs[0][d] + wj1 * L.a.wvs[1][d]
                   + wj2 * L.a.wvs[2][d] + wj3 * L.a.wvs[3][d];
        float oval = (o + corr) / lsum + L.a.wvs[4][d];
        if (lane < 32) AO[(b * 256 + s) * 256 + h * 32 + d] = oval;
      }
    }
    gbar(cnt, ++bi * 256u);

    // ---- S4: wo GEMM split-K=4 (256 tiles), atomic into X (pre-init src+bo) ----
    {
      int ks = bx >> 6, u = bx & 63;
      int m0 = (u >> 2) * 32, n0 = (u & 3) * 64;
      float acc[2][4] = {};
      gemm32(L, AO, 256, wo_l, 256, ks * 64, ks * 64 + 64, m0, n0, acc);
      int tx = tid & 15, ty = tid >> 4;
      int c0 = n0 + tx * 4;
#pragma unroll
      for (int i = 0; i < 2; ++i) {
        int m = m0 + ty * 2 + i;
        atomicAdd(&X[m * 256 + c0 + 0], acc[i][0]);
        atomicAdd(&X[m * 256 + c0 + 1], acc[i][1]);
        atomicAdd(&X[m * 256 + c0 + 2], acc[i][2]);
        atomicAdd(&X[m * 256 + c0 + 3], acc[i][3]);
      }
    }
    gbar(cnt, ++bi * 256u);

    // ---- S5: LN2 -> XN, outb := masked(X + b2) ----
    if (w < 2) {
      int row = bx * 2 + w;
      float4 v = ((const float4*)(X + row * 256))[lane];
      float s  = v.x + v.y + v.z + v.w;
      float ss = v.x*v.x + v.y*v.y + v.z*v.z + v.w*v.w;
#pragma unroll
      for (int off = 32; off >= 1; off >>= 1) {
        s  += __shfl_xor(s,  off);
        ss += __shfl_xor(ss, off);
      }
      float mean = s * (1.0f / 256.0f);
      float var  = ss * (1.0f / 256.0f) - mean * mean;
      float rstd = rsqrtf(var + 1e-5f);
      float4 gg = ((const float4*)g2)[lane];
      float4 b4 = ((const float4*)be2)[lane];
      float4 ov;
      ov.x = (v.x - mean) * rstd * gg.x + b4.x;
      ov.y = (v.y - mean) * rstd * gg.y + b4.y;
      ov.z = (v.z - mean) * rstd * gg.z + b4.z;
      ov.w = (v.w - mean) * rstd * gg.w + b4.w;
      ((float4*)(XN + row * 256))[lane] = ov;
      float mm = (smask[row] != 0) ? 0.0f : 1.0f;
      float4 b2v = ((const float4*)b2_l)[lane];
      float4 oi;
      oi.x = mm * (v.x + b2v.x);
      oi.y = mm * (v.y + b2v.y);
      oi.z = mm * (v.z + b2v.z);
      oi.w = mm * (v.w + b2v.w);
      ((float4*)(outb + row * 256))[lane] = oi;
    }
    gbar(cnt, ++bi * 256u);

    // ---- S6: FF1 GEMM + ReLU (256 tiles) ----
    {
      int m0 = (bx >> 4) * 32, n0 = (bx & 15) * 64;
      float acc[2][4] = {};
      gemm32(L, XN, 256, w1_l, 1024, 0, 256, m0, n0, acc);
      int tx = tid & 15, ty = tid >> 4;
      int c0 = n0 + tx * 4;
#pragma unroll
      for (int i = 0; i < 2; ++i) {
        int m = m0 + ty * 2 + i;
        float4 r;
        r.x = fmaxf(acc[i][0] + b1_l[c0 + 0], 0.0f);
        r.y = fmaxf(acc[i][1] + b1_l[c0 + 1], 0.0f);
        r.z = fmaxf(acc[i][2] + b1_l[c0 + 2], 0.0f);
        r.w = fmaxf(acc[i][3] + b1_l[c0 + 3], 0.0f);
        *(float4*)&H1[m * 1024 + c0] = r;
      }
    }
    gbar(cnt, ++bi * 256u);

    // ---- S7: FF2 GEMM split-K=4 (256 tiles), masked atomic into outb ----
    {
      int ks = bx >> 6, u = bx & 63;
      int m0 = (u >> 2) * 32, n0 = (u & 3) * 64;
      float acc[2][4] = {};
      gemm32(L, H1, 1024, w2_l, 256, ks * 256, ks * 256 + 256, m0, n0, acc);
      int tx = tid & 15, ty = tid >> 4;
      int c0 = n0 + tx * 4;
#pragma unroll
      for (int i = 0; i < 2; ++i) {
        int m = m0 + ty * 2 + i;
        float mm = (smask[m] != 0) ? 0.0f : 1.0f;
        atomicAdd(&outb[m * 256 + c0 + 0], mm * acc[i][0]);
        atomicAdd(&outb[m * 256 + c0 + 1], mm * acc[i][1]);
        atomicAdd(&outb[m * 256 + c0 + 2], mm * acc[i][2]);
        atomicAdd(&outb[m * 256 + c0 + 3], mm * acc[i][3]);
      }
    }
    if (l == 0) gbar(cnt, ++bi * 256u);   // SRC1 complete before layer-1 S1
  }
}

extern "C" void kernel_launch(void* const* d_in, const int* in_sizes, int n_in,
                              void* d_out, int out_size, void* d_ws, size_t ws_size,
                              hipStream_t stream)
{
  const float* src  = (const float*)d_in[0];
  const float* tgt  = (const float*)d_in[1];
  const float* rpe  = (const float*)d_in[2];
  const int*   smask = (const int*)d_in[3];
  const int*   tmask = (const int*)d_in[4];
  const float* ln1g = (const float*)d_in[5];
  const float* ln1b = (const float*)d_in[6];
  const float* lntg = (const float*)d_in[7];
  const float* lntb = (const float*)d_in[8];
  const float* ln2g = (const float*)d_in[9];
  const float* ln2b = (const float*)d_in[10];
  const float* wq = (const float*)d_in[11];
  const float* bq = (const float*)d_in[12];
  const float* wk = (const float*)d_in[13];
  const float* bk = (const float*)d_in[14];
  const float* wv = (const float*)d_in[15];
  const float* bv = (const float*)d_in[16];
  const float* wo = (const float*)d_in[17];
  const float* bo = (const float*)d_in[18];
  const float* wr = (const float*)d_in[19];
  const float* br = (const float*)d_in[20];
  const float* w1 = (const float*)d_in[21];
  const float* b1 = (const float*)d_in[22];
  const float* w2 = (const float*)d_in[23];
  const float* b2 = (const float*)d_in[24];

  float* ws = (float*)d_ws;
  unsigned* cnt = (unsigned*)(ws + 1703936);   // after H1 (1179648 + 524288)

  hipMemsetAsync(cnt, 0, 64, stream);          // barrier counter = 0 (graph-legal)
  mega_kernel<<<256, 256, 0, stream>>>(
      src, tgt, rpe, smask, tmask,
      ln1g, ln1b, lntg, lntb, ln2g, ln2b,
      wq, bq, wk, bk, wv, bv, wo, bo, wr, br, w1, b1, w2, b2,
      ws, (float*)d_out, cnt);
}

// Round 5
// 276.561 us; speedup vs baseline: 1.9594x; 1.9594x over previous
//
#include <hip/hip_runtime.h>
#include <math.h>

#define NEG_INF -1e30f

// =======================================================================
// qkv_ln: LN folded into A-staging. A (32 rows x 256) is LN'd in-register
// and stored transposed into As[k&31][k>>5][m] (pad 36 -> store <=2-way
// conflict, read conflict-free). K-loop stages only B.
// grid (4,16,3): n0=bx*64, m0=by*32, z: 0=Q(src,ln1) 1=K 2=V (tgt,lnt).
// z==0 && bx==0 blocks also write X := src + bo (raw rows, pre-residual).
// =======================================================================
__global__ __launch_bounds__(256) void qkv_ln_kernel(
    const float* __restrict__ srcin, const float* __restrict__ tgt,
    const float* __restrict__ g1, const float* __restrict__ b1,
    const float* __restrict__ gt, const float* __restrict__ bt,
    const float* __restrict__ bo,
    const float* __restrict__ wq, const float* __restrict__ wk, const float* __restrict__ wv,
    const float* __restrict__ bq, const float* __restrict__ bk, const float* __restrict__ bv,
    float* __restrict__ Qb, float* __restrict__ Kb, float* __restrict__ Vb,
    float* __restrict__ X)
{
  __shared__ float As[32][8][36];   // [k&31][k>>5][m], 36 KB
  __shared__ float Bs[32][64];      // 8 KB
  int z = blockIdx.z;
  int m0 = blockIdx.y * 32, n0 = blockIdx.x * 64;
  const float* Bw   = (z == 0) ? wq : (z == 1) ? wk : wv;
  const float* bias = (z == 0) ? bq : (z == 1) ? bk : bv;
  const float* g    = (z == 0) ? g1 : gt;
  const float* be   = (z == 0) ? b1 : bt;
  int tid = threadIdx.x;
  int r = tid >> 3, c4 = tid & 7;          // row m0+r, col-chunk c4*32..+31
  int row = m0 + r;
  const float* arow = ((z == 0) ? srcin : tgt) + (size_t)row * 256 + c4 * 32;

  float4 x[8];
  float s = 0, ss = 0;
#pragma unroll
  for (int j = 0; j < 8; ++j) {
    x[j] = ((const float4*)arow)[j];
    s  += x[j].x + x[j].y + x[j].z + x[j].w;
    ss += x[j].x*x[j].x + x[j].y*x[j].y + x[j].z*x[j].z + x[j].w*x[j].w;
  }
#pragma unroll
  for (int off = 1; off < 8; off <<= 1) {   // 8 lanes per row (tid = r*8+c4)
    s  += __shfl_xor(s,  off);
    ss += __shfl_xor(ss, off);
  }
  float mean = s * (1.0f / 256.0f);
  float var  = ss * (1.0f / 256.0f) - mean * mean;
  float rstd = rsqrtf(var + 1e-5f);
#pragma unroll
  for (int j = 0; j < 8; ++j) {
    float4 gg = ((const float4*)(g  + c4 * 32))[j];
    float4 bb = ((const float4*)(be + c4 * 32))[j];
    As[j*4+0][c4][r] = (x[j].x - mean) * rstd * gg.x + bb.x;
    As[j*4+1][c4][r] = (x[j].y - mean) * rstd * gg.y + bb.y;
    As[j*4+2][c4][r] = (x[j].z - mean) * rstd * gg.z + bb.z;
    As[j*4+3][c4][r] = (x[j].w - mean) * rstd * gg.w + bb.w;
  }
  if (z == 0 && blockIdx.x == 0) {          // X := src + bo (for wo atomics)
#pragma unroll
    for (int j = 0; j < 8; ++j) {
      float4 bo4 = ((const float4*)(bo + c4 * 32))[j];
      float4 xi;
      xi.x = x[j].x + bo4.x; xi.y = x[j].y + bo4.y;
      xi.z = x[j].z + bo4.z; xi.w = x[j].w + bo4.w;
      *(float4*)&X[(size_t)row * 256 + c4 * 32 + j * 4] = xi;
    }
  }
  __syncthreads();

  int tx = tid & 15, ty = tid >> 4;
  float acc[2][4] = {};
  for (int kc = 0; kc < 256; kc += 32) {
    const float* bp = Bw + (size_t)(kc + r) * 256 + n0;
    float4 b0  = *(const float4*)(bp + c4 * 4);
    float4 b1v = *(const float4*)(bp + 32 + c4 * 4);
    *(float4*)&Bs[r][c4 * 4]      = b0;
    *(float4*)&Bs[r][32 + c4 * 4] = b1v;
    __syncthreads();
    int kcc = kc >> 5;
#pragma unroll
    for (int kk = 0; kk < 32; ++kk) {
      float2 av = *(const float2*)&As[kk][kcc][ty * 2];
      float4 bv = *(const float4*)&Bs[kk][tx * 4];
      acc[0][0] = fmaf(av.x, bv.x, acc[0][0]); acc[0][1] = fmaf(av.x, bv.y, acc[0][1]);
      acc[0][2] = fmaf(av.x, bv.z, acc[0][2]); acc[0][3] = fmaf(av.x, bv.w, acc[0][3]);
      acc[1][0] = fmaf(av.y, bv.x, acc[1][0]); acc[1][1] = fmaf(av.y, bv.y, acc[1][1]);
      acc[1][2] = fmaf(av.y, bv.z, acc[1][2]); acc[1][3] = fmaf(av.y, bv.w, acc[1][3]);
    }
    __syncthreads();
  }

  int c0 = n0 + tx * 4;
  const float scale = 0.1767766952966369f;   // 1/sqrt(32)
#pragma unroll
  for (int i = 0; i < 2; ++i) {
    int m = m0 + ty * 2 + i;
    float4 rr;
    rr.x = acc[i][0] + bias[c0 + 0];
    rr.y = acc[i][1] + bias[c0 + 1];
    rr.z = acc[i][2] + bias[c0 + 2];
    rr.w = acc[i][3] + bias[c0 + 3];
    if (z == 0) {
      rr.x *= scale; rr.y *= scale; rr.z *= scale; rr.w *= scale;
      *(float4*)&Qb[m * 256 + c0] = rr;
    } else {
      int b = m >> 8, t = m & 255, h = c0 >> 5, d0 = c0 & 31;
      float* dst = ((z == 1) ? Kb : Vb) + (size_t)(b * 8 + h) * 8192 + t * 32 + d0;
      *(float4*)dst = rr;
    }
  }
}

// =======================================================================
// ff1_ln2: LN2 folded into A-staging (A = LN2(X)); ReLU epilogue -> H1.
// bx==0 blocks also write outb := mask*(X + b2)  (FF2 accumulator init).
// grid (16,16): n0=bx*64 (of 1024), m0=by*32.
// =======================================================================
__global__ __launch_bounds__(256) void ff1_ln2_kernel(
    const float* __restrict__ Xin,
    const float* __restrict__ g2, const float* __restrict__ be2,
    const float* __restrict__ b2, const int* __restrict__ smask,
    const float* __restrict__ w1, const float* __restrict__ b1,
    float* __restrict__ H1, float* __restrict__ outb)
{
  __shared__ float As[32][8][36];
  __shared__ float Bs[32][64];
  int m0 = blockIdx.y * 32, n0 = blockIdx.x * 64;
  int tid = threadIdx.x;
  int r = tid >> 3, c4 = tid & 7;
  int row = m0 + r;
  const float* arow = Xin + (size_t)row * 256 + c4 * 32;

  float4 x[8];
  float s = 0, ss = 0;
#pragma unroll
  for (int j = 0; j < 8; ++j) {
    x[j] = ((const float4*)arow)[j];
    s  += x[j].x + x[j].y + x[j].z + x[j].w;
    ss += x[j].x*x[j].x + x[j].y*x[j].y + x[j].z*x[j].z + x[j].w*x[j].w;
  }
#pragma unroll
  for (int off = 1; off < 8; off <<= 1) {
    s  += __shfl_xor(s,  off);
    ss += __shfl_xor(ss, off);
  }
  float mean = s * (1.0f / 256.0f);
  float var  = ss * (1.0f / 256.0f) - mean * mean;
  float rstd = rsqrtf(var + 1e-5f);
#pragma unroll
  for (int j = 0; j < 8; ++j) {
    float4 gg = ((const float4*)(g2  + c4 * 32))[j];
    float4 bb = ((const float4*)(be2 + c4 * 32))[j];
    As[j*4+0][c4][r] = (x[j].x - mean) * rstd * gg.x + bb.x;
    As[j*4+1][c4][r] = (x[j].y - mean) * rstd * gg.y + bb.y;
    As[j*4+2][c4][r] = (x[j].z - mean) * rstd * gg.z + bb.z;
    As[j*4+3][c4][r] = (x[j].w - mean) * rstd * gg.w + bb.w;
  }
  if (blockIdx.x == 0) {                    // outb := mask*(X + b2)
    float mm = (smask[row] != 0) ? 0.0f : 1.0f;
#pragma unroll
    for (int j = 0; j < 8; ++j) {
      float4 b24 = ((const float4*)(b2 + c4 * 32))[j];
      float4 oi;
      oi.x = mm * (x[j].x + b24.x); oi.y = mm * (x[j].y + b24.y);
      oi.z = mm * (x[j].z + b24.z); oi.w = mm * (x[j].w + b24.w);
      *(float4*)&outb[(size_t)row * 256 + c4 * 32 + j * 4] = oi;
    }
  }
  __syncthreads();

  int tx = tid & 15, ty = tid >> 4;
  float acc[2][4] = {};
  for (int kc = 0; kc < 256; kc += 32) {
    const float* bp = w1 + (size_t)(kc + r) * 1024 + n0;
    float4 b0  = *(const float4*)(bp + c4 * 4);
    float4 b1v = *(const float4*)(bp + 32 + c4 * 4);
    *(float4*)&Bs[r][c4 * 4]      = b0;
    *(float4*)&Bs[r][32 + c4 * 4] = b1v;
    __syncthreads();
    int kcc = kc >> 5;
#pragma unroll
    for (int kk = 0; kk < 32; ++kk) {
      float2 av = *(const float2*)&As[kk][kcc][ty * 2];
      float4 bv = *(const float4*)&Bs[kk][tx * 4];
      acc[0][0] = fmaf(av.x, bv.x, acc[0][0]); acc[0][1] = fmaf(av.x, bv.y, acc[0][1]);
      acc[0][2] = fmaf(av.x, bv.z, acc[0][2]); acc[0][3] = fmaf(av.x, bv.w, acc[0][3]);
      acc[1][0] = fmaf(av.y, bv.x, acc[1][0]); acc[1][1] = fmaf(av.y, bv.y, acc[1][1]);
      acc[1][2] = fmaf(av.y, bv.z, acc[1][2]); acc[1][3] = fmaf(av.y, bv.w, acc[1][3]);
    }
    __syncthreads();
  }

  int c0 = n0 + tx * 4;
#pragma unroll
  for (int i = 0; i < 2; ++i) {
    int m = m0 + ty * 2 + i;
    float4 rr;
    rr.x = fmaxf(acc[i][0] + b1[c0 + 0], 0.0f);
    rr.y = fmaxf(acc[i][1] + b1[c0 + 1], 0.0f);
    rr.z = fmaxf(acc[i][2] + b1[c0 + 2], 0.0f);
    rr.w = fmaxf(acc[i][3] + b1[c0 + 3], 0.0f);
    *(float4*)&H1[m * 1024 + c0] = rr;
  }
}

// ---------- GEMM core: 32x64 tile, 2x4 micro, 256 thr, KC=32 (wo/ff2) ----------
__device__ __forceinline__ void gemm_core32(
    const float* __restrict__ A, int lda,
    const float* __restrict__ Bw, int ldb,
    int kbeg, int kend, int m0, int n0,
    float acc[2][4])
{
  __shared__ float At[32][34];
  __shared__ float Bs[32][64];
  int tid = threadIdx.x;
  int tx = tid & 15, ty = tid >> 4;
  int r  = tid >> 3;
  int c4 = tid & 7;
  for (int kc = kbeg; kc < kend; kc += 32) {
    float4 a = *(const float4*)(A + (size_t)(m0 + r) * lda + kc + c4 * 4);
    const float* bp = Bw + (size_t)(kc + r) * ldb + n0;
    float4 b0 = *(const float4*)(bp + c4 * 4);
    float4 b1v = *(const float4*)(bp + 32 + c4 * 4);
    At[c4*4+0][r] = a.x; At[c4*4+1][r] = a.y; At[c4*4+2][r] = a.z; At[c4*4+3][r] = a.w;
    *(float4*)&Bs[r][c4*4]      = b0;
    *(float4*)&Bs[r][32 + c4*4] = b1v;
    __syncthreads();
#pragma unroll
    for (int k = 0; k < 32; ++k) {
      float2 av = *(const float2*)&At[k][ty * 2];
      float4 bv = *(const float4*)&Bs[k][tx * 4];
      acc[0][0] = fmaf(av.x, bv.x, acc[0][0]); acc[0][1] = fmaf(av.x, bv.y, acc[0][1]);
      acc[0][2] = fmaf(av.x, bv.z, acc[0][2]); acc[0][3] = fmaf(av.x, bv.w, acc[0][3]);
      acc[1][0] = fmaf(av.y, bv.x, acc[1][0]); acc[1][1] = fmaf(av.y, bv.y, acc[1][1]);
      acc[1][2] = fmaf(av.y, bv.z, acc[1][2]); acc[1][3] = fmaf(av.y, bv.w, acc[1][3]);
    }
    __syncthreads();
  }
}

// ---------- wo GEMM split-K=2, atomic into X (pre-init src+bo) ----------
__global__ __launch_bounds__(256) void wo_kernel(
    const float* __restrict__ AO, const float* __restrict__ wo,
    float* __restrict__ X)
{
  int m0 = blockIdx.y * 32, n0 = blockIdx.x * 64;
  int kbeg = blockIdx.z * 128;
  float acc[2][4] = {};
  gemm_core32(AO, 256, wo, 256, kbeg, kbeg + 128, m0, n0, acc);
  int tid = threadIdx.x, tx = tid & 15, ty = tid >> 4;
  int c0 = n0 + tx * 4;
#pragma unroll
  for (int i = 0; i < 2; ++i) {
    int m = m0 + ty * 2 + i;
    atomicAdd(&X[m * 256 + c0 + 0], acc[i][0]);
    atomicAdd(&X[m * 256 + c0 + 1], acc[i][1]);
    atomicAdd(&X[m * 256 + c0 + 2], acc[i][2]);
    atomicAdd(&X[m * 256 + c0 + 3], acc[i][3]);
  }
}

// ---------- FF2 split-K=4 GEMM, masked atomic accumulate : grid (4,16,4) ----------
__global__ __launch_bounds__(256) void ff2_kernel(
    const float* __restrict__ H1, const float* __restrict__ w2,
    const int* __restrict__ smask, float* __restrict__ outb)
{
  int m0 = blockIdx.y * 32, n0 = blockIdx.x * 64;
  int kbeg = blockIdx.z * 256;
  float acc[2][4] = {};
  gemm_core32(H1, 1024, w2, 256, kbeg, kbeg + 256, m0, n0, acc);
  int tid = threadIdx.x, tx = tid & 15, ty = tid >> 4;
  int c0 = n0 + tx * 4;
#pragma unroll
  for (int i = 0; i < 2; ++i) {
    int m = m0 + ty * 2 + i;
    float mm = (smask[m] != 0) ? 0.0f : 1.0f;
    atomicAdd(&outb[m * 256 + c0 + 0], mm * acc[i][0]);
    atomicAdd(&outb[m * 256 + c0 + 1], mm * acc[i][1]);
    atomicAdd(&outb[m * 256 + c0 + 2], mm * acc[i][2]);
    atomicAdd(&outb[m * 256 + c0 + 3], mm * acc[i][3]);
  }
}

// ---------- attention: block = (b,h,16 s-rows), 256 thr; K/V in LDS ----------
__global__ __launch_bounds__(256) void attn_kernel(
    const float* __restrict__ Qb, const float* __restrict__ Kb, const float* __restrict__ Vb,
    const float* __restrict__ rpe, const int* __restrict__ tmask,
    const float* __restrict__ wrl, const float* __restrict__ brl,
    float* __restrict__ AO)
{
  __shared__ float Ks[256][32];
  __shared__ float Vt[32][260];
  __shared__ float ps[4][256];
  __shared__ float qs[16][32];
  __shared__ float wks[5][32];
  __shared__ float wvs[5][32];
  int bid = blockIdx.x;
  int b = bid >> 7, h = (bid >> 4) & 7, s0 = (bid & 15) << 4;
  int tid = threadIdx.x;
  const float* Kp = Kb + (size_t)(b * 8 + h) * 8192;
  const float* Vp = Vb + (size_t)(b * 8 + h) * 8192;
  {
    int t = tid;
    const float4* kr = (const float4*)(Kp + t * 32);
    const float4* vr = (const float4*)(Vp + t * 32);
    int sw = t & 7;
#pragma unroll
    for (int c = 0; c < 8; ++c) {
      float4 k4 = kr[c];
      *(float4*)&Ks[t][(c ^ sw) * 4] = k4;
    }
#pragma unroll
    for (int c = 0; c < 8; ++c) {
      float4 v4 = vr[c];
      Vt[c*4+0][t] = v4.x; Vt[c*4+1][t] = v4.y; Vt[c*4+2][t] = v4.z; Vt[c*4+3][t] = v4.w;
    }
  }
  if (tid < 160) {
    int j = tid >> 5, d = tid & 31;
    wks[j][d] = (j < 4) ? wrl[j * 512 + h * 32 + d]       : brl[h * 32 + d];
    wvs[j][d] = (j < 4) ? wrl[j * 512 + 256 + h * 32 + d] : brl[256 + h * 32 + d];
  }
  if (tid >= 128) {
    int u = tid - 128;
    int rr2 = u >> 3, cc = u & 7;
    *(float4*)&qs[rr2][cc*4] =
        *(const float4*)&Qb[(b * 256 + s0 + rr2) * 256 + h * 32 + cc * 4];
  }
  __syncthreads();

  int w = tid >> 6, lane = tid & 63;
  int msk[4];
#pragma unroll
  for (int it = 0; it < 4; ++it) msk[it] = tmask[b * 256 + it * 64 + lane];

  for (int i = 0; i < 4; ++i) {
    int sl = w * 4 + i;
    int s = s0 + sl;
    float4 q4[8];
#pragma unroll
    for (int c = 0; c < 8; ++c) q4[c] = *(const float4*)&qs[sl][c * 4];
    float qw[4]; float qbr = 0.0f;
#pragma unroll
    for (int j = 0; j < 4; ++j) {
      float t0 = 0;
#pragma unroll
      for (int c = 0; c < 8; ++c) {
        float4 wv4 = *(const float4*)&wks[j][c * 4];
        t0 += q4[c].x*wv4.x + q4[c].y*wv4.y + q4[c].z*wv4.z + q4[c].w*wv4.w;
      }
      qw[j] = t0;
    }
#pragma unroll
    for (int c = 0; c < 8; ++c) {
      float4 wv4 = *(const float4*)&wks[4][c * 4];
      qbr += q4[c].x*wv4.x + q4[c].y*wv4.y + q4[c].z*wv4.z + q4[c].w*wv4.w;
    }
    const float4* rp4 = (const float4*)(rpe + (size_t)(b * 256 + s) * 1024);
    float sc[4]; float4 rr[4];
#pragma unroll
    for (int it = 0; it < 4; ++it) {
      int t = it * 64 + lane;
      int sw = t & 7;
      float sv = 0;
#pragma unroll
      for (int c = 0; c < 8; ++c) {
        float4 k4 = *(const float4*)&Ks[t][(c ^ sw) * 4];
        sv = fmaf(q4[c].x, k4.x, sv); sv = fmaf(q4[c].y, k4.y, sv);
        sv = fmaf(q4[c].z, k4.z, sv); sv = fmaf(q4[c].w, k4.w, sv);
      }
      float4 rv = rp4[t];
      rr[it] = rv;
      sv += rv.x*qw[0] + rv.y*qw[1] + rv.z*qw[2] + rv.w*qw[3] + qbr;
      if (msk[it] != 0) sv = NEG_INF;
      sc[it] = sv;
    }
    float mval = fmaxf(fmaxf(sc[0], sc[1]), fmaxf(sc[2], sc[3]));
#pragma unroll
    for (int off = 32; off >= 1; off >>= 1) mval = fmaxf(mval, __shfl_xor(mval, off));
    float p[4], lsum = 0;
#pragma unroll
    for (int it = 0; it < 4; ++it) { p[it] = __expf(sc[it] - mval); lsum += p[it]; }
    float wj0 = 0, wj1 = 0, wj2 = 0, wj3 = 0;
#pragma unroll
    for (int it = 0; it < 4; ++it) {
      wj0 = fmaf(p[it], rr[it].x, wj0);
      wj1 = fmaf(p[it], rr[it].y, wj1);
      wj2 = fmaf(p[it], rr[it].z, wj2);
      wj3 = fmaf(p[it], rr[it].w, wj3);
    }
#pragma unroll
    for (int off = 32; off >= 1; off >>= 1) {
      lsum += __shfl_xor(lsum, off);
      wj0 += __shfl_xor(wj0, off);
      wj1 += __shfl_xor(wj1, off);
      wj2 += __shfl_xor(wj2, off);
      wj3 += __shfl_xor(wj3, off);
    }
#pragma unroll
    for (int it = 0; it < 4; ++it) ps[w][it * 64 + lane] = p[it];
    int g = lane >> 5, d = lane & 31;
    float o = 0;
#pragma unroll
    for (int n = 0; n < 32; ++n) {
      int t = g * 128 + n * 4;
      float4 p4 = *(const float4*)&ps[w][t];
      float4 v4 = *(const float4*)&Vt[d][t];
      o += p4.x*v4.x + p4.y*v4.y + p4.z*v4.z + p4.w*v4.w;
    }
    o += __shfl_xor(o, 32);
    float corr = wj0 * wvs[0][d] + wj1 * wvs[1][d] + wj2 * wvs[2][d] + wj3 * wvs[3][d];
    float oval = (o + corr) / lsum + wvs[4][d];
    if (lane < 32) AO[(b * 256 + s) * 256 + h * 32 + d] = oval;
  }
}

extern "C" void kernel_launch(void* const* d_in, const int* in_sizes, int n_in,
                              void* d_out, int out_size, void* d_ws, size_t ws_size,
                              hipStream_t stream)
{
  const float* src  = (const float*)d_in[0];
  const float* tgt  = (const float*)d_in[1];
  const float* rpe  = (const float*)d_in[2];
  const int*   smask = (const int*)d_in[3];
  const int*   tmask = (const int*)d_in[4];
  const float* ln1g = (const float*)d_in[5];
  const float* ln1b = (const float*)d_in[6];
  const float* lntg = (const float*)d_in[7];
  const float* lntb = (const float*)d_in[8];
  const float* ln2g = (const float*)d_in[9];
  const float* ln2b = (const float*)d_in[10];
  const float* wq = (const float*)d_in[11];
  const float* bq = (const float*)d_in[12];
  const float* wk = (const float*)d_in[13];
  const float* bk = (const float*)d_in[14];
  const float* wv = (const float*)d_in[15];
  const float* bv = (const float*)d_in[16];
  const float* wo = (const float*)d_in[17];
  const float* bo = (const float*)d_in[18];
  const float* wr = (const float*)d_in[19];
  const float* br = (const float*)d_in[20];
  const float* w1 = (const float*)d_in[21];
  const float* b1 = (const float*)d_in[22];
  const float* w2 = (const float*)d_in[23];
  const float* b2 = (const float*)d_in[24];

  float* ws   = (float*)d_ws;
  float* Qb   = ws;
  float* Kb   = ws + 131072;
  float* Vb   = ws + 262144;
  float* AO   = ws + 393216;
  float* X    = ws + 524288;
  float* SRC1 = ws + 655360;
  float* H1   = ws + 786432;   // 524288 floats

  for (int l = 0; l < 2; ++l) {
    const float* srcin = l ? SRC1 : src;
    float* outb = l ? (float*)d_out : SRC1;
    qkv_ln_kernel<<<dim3(4, 16, 3), 256, 0, stream>>>(
        srcin, tgt, ln1g + l*256, ln1b + l*256, lntg + l*256, lntb + l*256,
        bo + l*256,
        wq + l*65536, wk + l*65536, wv + l*65536,
        bq + l*256, bk + l*256, bv + l*256,
        Qb, Kb, Vb, X);
    attn_kernel<<<256, 256, 0, stream>>>(Qb, Kb, Vb, rpe, tmask,
                                         wr + l*2048, br + l*512, AO);
    wo_kernel<<<dim3(4, 16, 2), 256, 0, stream>>>(AO, wo + l*65536, X);
    ff1_ln2_kernel<<<dim3(16, 16), 256, 0, stream>>>(
        X, ln2g + l*256, ln2b + l*256, b2 + l*256, smask,
        w1 + l*262144, b1 + l*1024, H1, outb);
    ff2_kernel<<<dim3(4, 16, 4), 256, 0, stream>>>(H1, w2 + l*262144, smask, outb);
  }
}